// Round 4
// baseline (257.396 us; speedup 1.0000x reference)
//
#include <hip/hip_runtime.h>
#include <stdint.h>

#define D 512
#define KTOT 1024       // [hi | lo] split, correction term xl*mh
#define BATCH 8192
#define NMAP 1024
#define GRID_W 32
#define ALPHA 0.5f
#define C2 15.859712f   // 2*(35.2*0.08)^2

typedef __attribute__((ext_vector_type(4))) float f32x4;
typedef __attribute__((ext_vector_type(8))) short bf16x8;
typedef __attribute__((ext_vector_type(8))) unsigned short u16x8;

static __device__ __forceinline__ unsigned short f2bf(float f) {
    uint32_t u = __float_as_uint(f);
    uint32_t r = (u + 0x7FFFu + ((u >> 16) & 1u)) >> 16;
    return (unsigned short)r;
}
static __device__ __forceinline__ float bf2f(unsigned short h) {
    return __uint_as_float(((uint32_t)h) << 16);
}

// ---------------- prep: split x -> As=[xh|xl], init packed,
//                  split map -> Bs=[mh|mh], m2 ----------------
__global__ __launch_bounds__(256) void k_prep(const float* __restrict__ x,
                                              const float* __restrict__ map,
                                              unsigned short* __restrict__ As,
                                              unsigned short* __restrict__ Bs,
                                              float* __restrict__ m2,
                                              unsigned long long* __restrict__ packed) {
    int bid = blockIdx.x;
    if (bid < BATCH * (D / 8) / 256) {
        // ---- x part: one thread per 8 elements ----
        int g = bid * 256 + threadIdx.x;
        if (g < BATCH) packed[g] = 0xFFFFFFFFFFFFFFFFull;
        int b = g >> 6;
        int k8 = (g & 63) << 3;
        const float* xp = x + (size_t)b * D + k8;
        float4 v0 = *(const float4*)xp;
        float4 v1 = *(const float4*)(xp + 4);
        float vv[8] = {v0.x, v0.y, v0.z, v0.w, v1.x, v1.y, v1.z, v1.w};
        u16x8 hi, lo;
        #pragma unroll
        for (int j = 0; j < 8; j++) {
            unsigned short h = f2bf(vv[j]);
            hi[j] = h;
            lo[j] = f2bf(vv[j] - bf2f(h));
        }
        unsigned short* row = As + (size_t)b * KTOT;
        *(u16x8*)(row + k8) = hi;
        *(u16x8*)(row + 512 + k8) = lo;
    } else {
        // ---- map part: one wave per map row, 4 rows per block ----
        int mb = bid - BATCH * (D / 8) / 256;
        int n = mb * 4 + (threadIdx.x >> 6);
        int lane = threadIdx.x & 63;
        const float* mp = map + (size_t)n * D + lane * 8;
        float4 v0 = *(const float4*)mp;
        float4 v1 = *(const float4*)(mp + 4);
        float vv[8] = {v0.x, v0.y, v0.z, v0.w, v1.x, v1.y, v1.z, v1.w};
        u16x8 hi;
        float s = 0.f;
        #pragma unroll
        for (int j = 0; j < 8; j++) {
            s += vv[j] * vv[j];
            hi[j] = f2bf(vv[j]);
        }
        unsigned short* row = Bs + (size_t)n * KTOT;
        *(u16x8*)(row + lane * 8) = hi;
        *(u16x8*)(row + 512 + lane * 8) = hi;
        #pragma unroll
        for (int off = 32; off > 0; off >>= 1) s += __shfl_down(s, off);
        if (lane == 0) m2[n] = s;
    }
}

// ---------------- BMU: bf16 MFMA GEMM + fused argmin ----------------
// dist[b,n] = m2[n] - 2*(xh.mh + xl.mh); argmin_n per row b.
// 128x128 tile, BK=64, 4 waves (2x2), 16x16x32 MFMA, st-swizzled LDS.
// 1-D grid with bijective XCD swizzle: 512 blocks = 8 XCDs x 64; each XCD
// gets one full B-panel stripe (same n0) -> Bs tile stays in its L2.
#define BM 128
#define BN 128
#define BK 64

__global__ __launch_bounds__(256) void k_bmu(const unsigned short* __restrict__ As,
                                             const unsigned short* __restrict__ Bs,
                                             const float* __restrict__ m2,
                                             unsigned long long* __restrict__ packed) {
    __shared__ unsigned short Al[BM * BK];  // 16 KB
    __shared__ unsigned short Bl[BN * BK];  // 16 KB
    int wg = (blockIdx.x & 7) * 64 + (blockIdx.x >> 3);  // XCD swizzle (512%8==0)
    const int b0 = (wg & 63) * BM;
    const int n0 = (wg >> 6) * BN;
    const int t = threadIdx.x;
    const int w = t >> 6, l = t & 63;
    const int wm = w >> 1, wn = w & 1;

    f32x4 acc[4][4];
    #pragma unroll
    for (int i = 0; i < 4; i++)
        #pragma unroll
        for (int j = 0; j < 4; j++) acc[i][j] = (f32x4)(0.f);

    // wave w stages rows [w*32, w*32+32): 4 issues x 64 lanes x 16B.
    // LDS linear; source carries the inverse st-swizzle (slot ^ row&7).
    const int srow = l >> 3;
    const int sslot = (l & 7) ^ (l >> 3);
    const unsigned short* agp0 = As + (size_t)(b0 + w * 32 + srow) * KTOT + sslot * 8;
    const unsigned short* bgp0 = Bs + (size_t)(n0 + w * 32 + srow) * KTOT + sslot * 8;

    for (int kt = 0; kt < KTOT; kt += BK) {
        #pragma unroll
        for (int i = 0; i < 4; i++) {
            __builtin_amdgcn_global_load_lds(
                (const __attribute__((address_space(1))) void*)(agp0 + (size_t)i * 8 * KTOT + kt),
                (__attribute__((address_space(3))) void*)(Al + w * 2048 + i * 512), 16, 0, 0);
            __builtin_amdgcn_global_load_lds(
                (const __attribute__((address_space(1))) void*)(bgp0 + (size_t)i * 8 * KTOT + kt),
                (__attribute__((address_space(3))) void*)(Bl + w * 2048 + i * 512), 16, 0, 0);
        }
        __syncthreads();

        #pragma unroll
        for (int kk = 0; kk < 2; kk++) {
            bf16x8 af[4], bfr[4];
            #pragma unroll
            for (int mi = 0; mi < 4; mi++) {
                int r = wm * 64 + mi * 16 + (l & 15);
                int slot = kk * 4 + (l >> 4);
                af[mi] = *(const bf16x8*)&Al[r * 64 + ((slot ^ (r & 7)) << 3)];
            }
            #pragma unroll
            for (int nj = 0; nj < 4; nj++) {
                int r = wn * 64 + nj * 16 + (l & 15);
                int slot = kk * 4 + (l >> 4);
                bfr[nj] = *(const bf16x8*)&Bl[r * 64 + ((slot ^ (r & 7)) << 3)];
            }
            #pragma unroll
            for (int mi = 0; mi < 4; mi++)
                #pragma unroll
                for (int nj = 0; nj < 4; nj++)
                    acc[mi][nj] = __builtin_amdgcn_mfma_f32_16x16x32_bf16(
                        af[mi], bfr[nj], acc[mi][nj], 0, 0, 0);
        }
        __syncthreads();
    }

    // ---- fused argmin epilogue ----
    float m2v[4];
    #pragma unroll
    for (int nj = 0; nj < 4; nj++)
        m2v[nj] = m2[n0 + wn * 64 + nj * 16 + (l & 15)];

    #pragma unroll
    for (int mi = 0; mi < 4; mi++) {
        #pragma unroll
        for (int reg = 0; reg < 4; reg++) {
            float best = m2v[0] - 2.0f * acc[mi][0][reg];
            int bi = n0 + wn * 64 + (l & 15);
            #pragma unroll
            for (int nj = 1; nj < 4; nj++) {
                float v = m2v[nj] - 2.0f * acc[mi][nj][reg];
                int n = n0 + wn * 64 + nj * 16 + (l & 15);
                if (v < best) { best = v; bi = n; }
            }
            #pragma unroll
            for (int msk = 1; msk <= 8; msk <<= 1) {
                float ov = __shfl_xor(best, msk);
                int oi = __shfl_xor(bi, msk);
                if (ov < best || (ov == best && oi < bi)) { best = ov; bi = oi; }
            }
            if ((l & 15) == 0) {
                unsigned int fb = __float_as_uint(best);
                fb = (fb & 0x80000000u) ? ~fb : (fb | 0x80000000u);
                unsigned long long key =
                    ((unsigned long long)fb << 32) | (unsigned int)bi;
                int row = b0 + wm * 64 + mi * 16 + (l >> 4) * 4 + reg;
                atomicMin(&packed[row], key);
            }
        }
    }
}

// ---------------- deterministic scatter-sum (reads packed directly) --------
__global__ __launch_bounds__(256) void k_scatter(const float* __restrict__ x,
                                                 const unsigned long long* __restrict__ packed,
                                                 float* __restrict__ S,
                                                 int* __restrict__ cnt) {
    __shared__ int list[BATCH];
    __shared__ int cnts[256];
    __shared__ int offs[256];
    int g = blockIdx.x;
    int t = threadIdx.x;
    int b0 = t * (BATCH / 256);

    int mybmu[BATCH / 256];
    int c = 0;
    #pragma unroll
    for (int i = 0; i < BATCH / 256; i++) {
        mybmu[i] = (int)(packed[b0 + i] & 0xFFFFFFFFull);
        c += (mybmu[i] == g) ? 1 : 0;
    }
    cnts[t] = c;
    offs[t] = c;
    __syncthreads();
    // Hillis-Steele inclusive scan over 256 entries
    #pragma unroll
    for (int s = 1; s < 256; s <<= 1) {
        int v = (t >= s) ? offs[t - s] : 0;
        __syncthreads();
        offs[t] += v;
        __syncthreads();
    }
    int off = offs[t] - cnts[t];  // exclusive
    #pragma unroll
    for (int i = 0; i < BATCH / 256; i++) {
        if (mybmu[i] == g) list[off++] = b0 + i;
    }
    __syncthreads();
    int len = offs[255];

    float acc0 = 0.f, acc1 = 0.f;
    for (int i = 0; i < len; i++) {
        const float* xr = x + (size_t)list[i] * D;
        acc0 += xr[t];
        acc1 += xr[t + 256];
    }
    S[(size_t)g * D + t] = acc0;
    S[(size_t)g * D + t + 256] = acc1;
    if (t == 0) cnt[g] = len;
}

// ---------------- post: conv-j + sum_lr + conv-i + epilogue ----------------
// block (nj, dblk): out[(ni*32+nj), d] for all ni, d in dblk.
// Bitwise-identical loop order to the previous conv1/conv2 pair.
__global__ __launch_bounds__(256) void k_post(const float* __restrict__ S,
                                              const int* __restrict__ cnt,
                                              const float* __restrict__ map,
                                              float* __restrict__ out) {
    __shared__ float tbl[GRID_W];
    __shared__ float vc[GRID_W];
    __shared__ float slr[GRID_W];
    int nj = blockIdx.x;
    int d = blockIdx.y * 256 + threadIdx.x;
    int t = threadIdx.x;
    if (t < GRID_W) tbl[t] = __expf(-(float)(t * t) / C2);
    __syncthreads();
    // sum_lr slice for this nj: vc[gi] = sum_gj tbl|nj-gj| * cnt[gi*32+gj]
    if (t < GRID_W) {
        float s = 0.f;
        for (int gj = 0; gj < GRID_W; gj++) {
            int dd = gj - nj; dd = dd < 0 ? -dd : dd;
            s += tbl[dd] * (float)cnt[t * GRID_W + gj];
        }
        vc[t] = s;
    }
    __syncthreads();
    if (t < GRID_W) {
        float s2 = 0.f;
        for (int gi = 0; gi < GRID_W; gi++) {
            int dd = gi - t; dd = dd < 0 ? -dd : dd;
            s2 += tbl[dd] * vc[gi];
        }
        slr[t] = ALPHA * s2;  // sum_lr[t*32 + nj]
    }
    __syncthreads();

    float T[GRID_W];
    #pragma unroll
    for (int gi = 0; gi < GRID_W; gi++) {
        float s = 0.f;
        for (int gj = 0; gj < GRID_W; gj++) {
            int dd = nj - gj; dd = dd < 0 ? -dd : dd;
            s += tbl[dd] * S[(size_t)(gi * GRID_W + gj) * D + d];
        }
        T[gi] = s;
    }
    #pragma unroll
    for (int ni = 0; ni < GRID_W; ni++) {
        float u = 0.f;
        #pragma unroll
        for (int gi = 0; gi < GRID_W; gi++) {
            int dd = ni - gi; dd = dd < 0 ? -dd : dd;
            u += tbl[dd] * T[gi];
        }
        int n = ni * GRID_W + nj;
        out[(size_t)n * D + d] =
            map[(size_t)n * D + d] * (1.0f - slr[ni]) + ALPHA * u;
    }
}

// ---------------- launcher ----------------
extern "C" void kernel_launch(void* const* d_in, const int* in_sizes, int n_in,
                              void* d_out, int out_size, void* d_ws, size_t ws_size,
                              hipStream_t stream) {
    (void)in_sizes; (void)n_in; (void)out_size; (void)ws_size;
    const float* x = (const float*)d_in[0];
    const float* map = (const float*)d_in[1];
    float* out = (float*)d_out;

    char* ws = (char*)d_ws;
    unsigned long long* packed = (unsigned long long*)(ws);          // 64 KB
    float* m2 = (float*)(ws + 65536);                                // 4 KB
    int* cnt = (int*)(ws + 69632);                                   // 4 KB
    float* S = (float*)(ws + 73728);                                 // 2 MB
    unsigned short* As = (unsigned short*)(ws + 2170880);            // 16 MB
    unsigned short* Bs = (unsigned short*)(ws + 2170880 + 16777216); // 2 MB

    k_prep<<<BATCH * (D / 8) / 256 + NMAP / 4, 256, 0, stream>>>(x, map, As, Bs, m2, packed);
    k_bmu<<<(BATCH / BM) * (NMAP / BN), 256, 0, stream>>>(As, Bs, m2, packed);
    k_scatter<<<NMAP, 256, 0, stream>>>(x, packed, S, cnt);
    k_post<<<dim3(GRID_W, D / 256), 256, 0, stream>>>(S, cnt, map, out);
}

// Round 5
// 99.910 us; speedup vs baseline: 2.5763x; 2.5763x over previous
//
#include <hip/hip_runtime.h>
#include <stdint.h>

#define D 512
#define KTOT 1024       // [hi | lo] split, correction term xl*mh
#define BATCH 8192
#define NMAP 1024
#define GRID_W 32
#define ALPHA 0.5f
#define C2 15.859712f   // 2*(35.2*0.08)^2

typedef __attribute__((ext_vector_type(4))) float f32x4;
typedef __attribute__((ext_vector_type(8))) short bf16x8;
typedef __attribute__((ext_vector_type(8))) unsigned short u16x8;

static __device__ __forceinline__ unsigned short f2bf(float f) {
    uint32_t u = __float_as_uint(f);
    uint32_t r = (u + 0x7FFFu + ((u >> 16) & 1u)) >> 16;
    return (unsigned short)r;
}
static __device__ __forceinline__ float bf2f(unsigned short h) {
    return __uint_as_float(((uint32_t)h) << 16);
}

// ---------------- prep: split x -> As=[xh|xl], init packed,
//                  split map -> Bs=[mh|mh], m2 ----------------
__global__ __launch_bounds__(256) void k_prep(const float* __restrict__ x,
                                              const float* __restrict__ map,
                                              unsigned short* __restrict__ As,
                                              unsigned short* __restrict__ Bs,
                                              float* __restrict__ m2,
                                              unsigned long long* __restrict__ packed) {
    int bid = blockIdx.x;
    if (bid < BATCH * (D / 8) / 256) {
        // ---- x part: one thread per 8 elements ----
        int g = bid * 256 + threadIdx.x;
        if (g < BATCH) packed[g] = 0xFFFFFFFFFFFFFFFFull;
        int b = g >> 6;
        int k8 = (g & 63) << 3;
        const float* xp = x + (size_t)b * D + k8;
        float4 v0 = *(const float4*)xp;
        float4 v1 = *(const float4*)(xp + 4);
        float vv[8] = {v0.x, v0.y, v0.z, v0.w, v1.x, v1.y, v1.z, v1.w};
        u16x8 hi, lo;
        #pragma unroll
        for (int j = 0; j < 8; j++) {
            unsigned short h = f2bf(vv[j]);
            hi[j] = h;
            lo[j] = f2bf(vv[j] - bf2f(h));
        }
        unsigned short* row = As + (size_t)b * KTOT;
        *(u16x8*)(row + k8) = hi;
        *(u16x8*)(row + 512 + k8) = lo;
    } else {
        // ---- map part: one wave per map row, 4 rows per block ----
        int mb = bid - BATCH * (D / 8) / 256;
        int n = mb * 4 + (threadIdx.x >> 6);
        int lane = threadIdx.x & 63;
        const float* mp = map + (size_t)n * D + lane * 8;
        float4 v0 = *(const float4*)mp;
        float4 v1 = *(const float4*)(mp + 4);
        float vv[8] = {v0.x, v0.y, v0.z, v0.w, v1.x, v1.y, v1.z, v1.w};
        u16x8 hi;
        float s = 0.f;
        #pragma unroll
        for (int j = 0; j < 8; j++) {
            s += vv[j] * vv[j];
            hi[j] = f2bf(vv[j]);
        }
        unsigned short* row = Bs + (size_t)n * KTOT;
        *(u16x8*)(row + lane * 8) = hi;
        *(u16x8*)(row + 512 + lane * 8) = hi;
        #pragma unroll
        for (int off = 32; off > 0; off >>= 1) s += __shfl_down(s, off);
        if (lane == 0) m2[n] = s;
    }
}

// ---------------- BMU: bf16 MFMA GEMM + fused argmin ----------------
// dist[b,n] = m2[n] - 2*(xh.mh + xl.mh); argmin_n per row b.
// 128x128 tile, BK=64, 4 waves (2x2), 16x16x32 MFMA, st-swizzled LDS.
// 1-D grid, bijective XCD swizzle (512 = 8 x 64): each XCD gets one full
// B-panel stripe -> Bs tile resident in its L2.
#define BM 128
#define BN 128
#define BK 64

__global__ __launch_bounds__(256) void k_bmu(const unsigned short* __restrict__ As,
                                             const unsigned short* __restrict__ Bs,
                                             const float* __restrict__ m2,
                                             unsigned long long* __restrict__ packed) {
    __shared__ unsigned short Al[BM * BK];  // 16 KB
    __shared__ unsigned short Bl[BN * BK];  // 16 KB
    int wg = (blockIdx.x & 7) * 64 + (blockIdx.x >> 3);  // XCD swizzle
    const int b0 = (wg & 63) * BM;
    const int n0 = (wg >> 6) * BN;
    const int t = threadIdx.x;
    const int w = t >> 6, l = t & 63;
    const int wm = w >> 1, wn = w & 1;

    f32x4 acc[4][4];
    #pragma unroll
    for (int i = 0; i < 4; i++)
        #pragma unroll
        for (int j = 0; j < 4; j++) acc[i][j] = (f32x4)(0.f);

    // wave w stages rows [w*32, w*32+32): 4 issues x 64 lanes x 16B.
    // LDS linear; source carries the inverse st-swizzle (slot ^ row&7).
    const int srow = l >> 3;
    const int sslot = (l & 7) ^ (l >> 3);
    const unsigned short* agp0 = As + (size_t)(b0 + w * 32 + srow) * KTOT + sslot * 8;
    const unsigned short* bgp0 = Bs + (size_t)(n0 + w * 32 + srow) * KTOT + sslot * 8;

    for (int kt = 0; kt < KTOT; kt += BK) {
        #pragma unroll
        for (int i = 0; i < 4; i++) {
            __builtin_amdgcn_global_load_lds(
                (const __attribute__((address_space(1))) void*)(agp0 + (size_t)i * 8 * KTOT + kt),
                (__attribute__((address_space(3))) void*)(Al + w * 2048 + i * 512), 16, 0, 0);
            __builtin_amdgcn_global_load_lds(
                (const __attribute__((address_space(1))) void*)(bgp0 + (size_t)i * 8 * KTOT + kt),
                (__attribute__((address_space(3))) void*)(Bl + w * 2048 + i * 512), 16, 0, 0);
        }
        __syncthreads();

        #pragma unroll
        for (int kk = 0; kk < 2; kk++) {
            bf16x8 af[4], bfr[4];
            #pragma unroll
            for (int mi = 0; mi < 4; mi++) {
                int r = wm * 64 + mi * 16 + (l & 15);
                int slot = kk * 4 + (l >> 4);
                af[mi] = *(const bf16x8*)&Al[r * 64 + ((slot ^ (r & 7)) << 3)];
            }
            #pragma unroll
            for (int nj = 0; nj < 4; nj++) {
                int r = wn * 64 + nj * 16 + (l & 15);
                int slot = kk * 4 + (l >> 4);
                bfr[nj] = *(const bf16x8*)&Bl[r * 64 + ((slot ^ (r & 7)) << 3)];
            }
            #pragma unroll
            for (int mi = 0; mi < 4; mi++)
                #pragma unroll
                for (int nj = 0; nj < 4; nj++)
                    acc[mi][nj] = __builtin_amdgcn_mfma_f32_16x16x32_bf16(
                        af[mi], bfr[nj], acc[mi][nj], 0, 0, 0);
        }
        __syncthreads();
    }

    // ---- fused argmin epilogue ----
    float m2v[4];
    #pragma unroll
    for (int nj = 0; nj < 4; nj++)
        m2v[nj] = m2[n0 + wn * 64 + nj * 16 + (l & 15)];

    #pragma unroll
    for (int mi = 0; mi < 4; mi++) {
        #pragma unroll
        for (int reg = 0; reg < 4; reg++) {
            float best = m2v[0] - 2.0f * acc[mi][0][reg];
            int bi = n0 + wn * 64 + (l & 15);
            #pragma unroll
            for (int nj = 1; nj < 4; nj++) {
                float v = m2v[nj] - 2.0f * acc[mi][nj][reg];
                int n = n0 + wn * 64 + nj * 16 + (l & 15);
                if (v < best) { best = v; bi = n; }
            }
            #pragma unroll
            for (int msk = 1; msk <= 8; msk <<= 1) {
                float ov = __shfl_xor(best, msk);
                int oi = __shfl_xor(bi, msk);
                if (ov < best || (ov == best && oi < bi)) { best = ov; bi = oi; }
            }
            if ((l & 15) == 0) {
                unsigned int fb = __float_as_uint(best);
                fb = (fb & 0x80000000u) ? ~fb : (fb | 0x80000000u);
                unsigned long long key =
                    ((unsigned long long)fb << 32) | (unsigned int)bi;
                int row = b0 + wm * 64 + mi * 16 + (l >> 4) * 4 + reg;
                atomicMin(&packed[row], key);
            }
        }
    }
}

// ---------------- deterministic scatter-sum (reads packed directly) --------
__global__ __launch_bounds__(256) void k_scatter(const float* __restrict__ x,
                                                 const unsigned long long* __restrict__ packed,
                                                 float* __restrict__ S,
                                                 int* __restrict__ cnt) {
    __shared__ int list[BATCH];
    __shared__ int cnts[256];
    __shared__ int offs[256];
    int g = blockIdx.x;
    int t = threadIdx.x;
    int b0 = t * (BATCH / 256);

    int mybmu[BATCH / 256];
    int c = 0;
    #pragma unroll
    for (int i = 0; i < BATCH / 256; i++) {
        mybmu[i] = (int)(packed[b0 + i] & 0xFFFFFFFFull);
        c += (mybmu[i] == g) ? 1 : 0;
    }
    cnts[t] = c;
    offs[t] = c;
    __syncthreads();
    // Hillis-Steele inclusive scan over 256 entries
    #pragma unroll
    for (int s = 1; s < 256; s <<= 1) {
        int v = (t >= s) ? offs[t - s] : 0;
        __syncthreads();
        offs[t] += v;
        __syncthreads();
    }
    int off = offs[t] - cnts[t];  // exclusive
    #pragma unroll
    for (int i = 0; i < BATCH / 256; i++) {
        if (mybmu[i] == g) list[off++] = b0 + i;
    }
    __syncthreads();
    int len = offs[255];

    float acc0 = 0.f, acc1 = 0.f;
    for (int i = 0; i < len; i++) {
        const float* xr = x + (size_t)list[i] * D;
        acc0 += xr[t];
        acc1 += xr[t + 256];
    }
    S[(size_t)g * D + t] = acc0;
    S[(size_t)g * D + t + 256] = acc1;
    if (t == 0) cnt[g] = len;
}

// ---------------- separable conv axis j (+ sum_lr in block (0,0)) ----------
__global__ __launch_bounds__(256) void k_conv1(const float* __restrict__ S,
                                               float* __restrict__ V,
                                               const int* __restrict__ cnt,
                                               float* __restrict__ sum_lr) {
    __shared__ float tbl[GRID_W];
    __shared__ float vc[GRID_W][GRID_W];
    int gi = blockIdx.x;
    int d = blockIdx.y * 256 + threadIdx.x;
    if (threadIdx.x < GRID_W)
        tbl[threadIdx.x] = __expf(-(float)(threadIdx.x * threadIdx.x) / C2);
    __syncthreads();
    float acc[GRID_W];
    #pragma unroll
    for (int nj = 0; nj < GRID_W; nj++) acc[nj] = 0.f;
    for (int gj = 0; gj < GRID_W; gj++) {
        float s = S[(size_t)(gi * GRID_W + gj) * D + d];
        #pragma unroll
        for (int nj = 0; nj < GRID_W; nj++) {
            int dd = nj - gj; dd = dd < 0 ? -dd : dd;
            acc[nj] += tbl[dd] * s;
        }
    }
    #pragma unroll
    for (int nj = 0; nj < GRID_W; nj++)
        V[(size_t)(gi * GRID_W + nj) * D + d] = acc[nj];

    // ---- sum_lr (separable over counts), one block does it all ----
    if (blockIdx.x == 0 && blockIdx.y == 0) {
        int t = threadIdx.x;
        #pragma unroll
        for (int j = 0; j < 4; j++) {
            int idx = t * 4 + j;
            int a = idx >> 5, b = idx & 31;
            float s = 0.f;
            for (int gj = 0; gj < GRID_W; gj++) {
                int dd = gj - b; dd = dd < 0 ? -dd : dd;
                s += tbl[dd] * (float)cnt[a * GRID_W + gj];
            }
            vc[a][b] = s;
        }
        __syncthreads();
        #pragma unroll
        for (int j = 0; j < 4; j++) {
            int idx = t * 4 + j;
            int a = idx >> 5, b = idx & 31;
            float s2 = 0.f;
            for (int gg = 0; gg < GRID_W; gg++) {
                int dd = gg - a; dd = dd < 0 ? -dd : dd;
                s2 += tbl[dd] * vc[gg][b];
            }
            sum_lr[idx] = ALPHA * s2;
        }
    }
}

// ---------------- separable conv axis i + epilogue ----------------
__global__ __launch_bounds__(256) void k_conv2(const float* __restrict__ V,
                                               const float* __restrict__ map,
                                               const float* __restrict__ sum_lr,
                                               float* __restrict__ out) {
    __shared__ float tbl[GRID_W];
    int nj = blockIdx.x;
    int d = blockIdx.y * 256 + threadIdx.x;
    if (threadIdx.x < GRID_W)
        tbl[threadIdx.x] = __expf(-(float)(threadIdx.x * threadIdx.x) / C2);
    __syncthreads();
    float acc[GRID_W];
    #pragma unroll
    for (int ni = 0; ni < GRID_W; ni++) acc[ni] = 0.f;
    for (int gi = 0; gi < GRID_W; gi++) {
        float v = V[(size_t)(gi * GRID_W + nj) * D + d];
        #pragma unroll
        for (int ni = 0; ni < GRID_W; ni++) {
            int dd = ni - gi; dd = dd < 0 ? -dd : dd;
            acc[ni] += tbl[dd] * v;
        }
    }
    #pragma unroll
    for (int ni = 0; ni < GRID_W; ni++) {
        int n = ni * GRID_W + nj;
        out[(size_t)n * D + d] =
            map[(size_t)n * D + d] * (1.0f - sum_lr[n]) + ALPHA * acc[ni];
    }
}

// ---------------- launcher ----------------
extern "C" void kernel_launch(void* const* d_in, const int* in_sizes, int n_in,
                              void* d_out, int out_size, void* d_ws, size_t ws_size,
                              hipStream_t stream) {
    (void)in_sizes; (void)n_in; (void)out_size; (void)ws_size;
    const float* x = (const float*)d_in[0];
    const float* map = (const float*)d_in[1];
    float* out = (float*)d_out;

    char* ws = (char*)d_ws;
    unsigned long long* packed = (unsigned long long*)(ws);          // 64 KB
    float* m2 = (float*)(ws + 65536);                                // 4 KB
    int* cnt = (int*)(ws + 69632);                                   // 4 KB
    float* sum_lr = (float*)(ws + 73728);                            // 4 KB
    float* S = (float*)(ws + 77824);                                 // 2 MB
    float* V = (float*)(ws + 2174976);                               // 2 MB
    unsigned short* As = (unsigned short*)(ws + 4272128);            // 16 MB
    unsigned short* Bs = (unsigned short*)(ws + 21049344);           // 2 MB

    k_prep<<<BATCH * (D / 8) / 256 + NMAP / 4, 256, 0, stream>>>(x, map, As, Bs, m2, packed);
    k_bmu<<<(BATCH / BM) * (NMAP / BN), 256, 0, stream>>>(As, Bs, m2, packed);
    k_scatter<<<NMAP, 256, 0, stream>>>(x, packed, S, cnt);
    k_conv1<<<dim3(GRID_W, D / 256), 256, 0, stream>>>(S, V, cnt, sum_lr);
    k_conv2<<<dim3(GRID_W, D / 256), 256, 0, stream>>>(V, map, sum_lr, out);
}

// Round 6
// 98.389 us; speedup vs baseline: 2.6161x; 1.0155x over previous
//
#include <hip/hip_runtime.h>
#include <stdint.h>

#define D 512
#define KTOT 1024       // A = [xh | xl]; B dedup'd to [mh] (stride 512)
#define BATCH 8192
#define NMAP 1024
#define GRID_W 32
#define ALPHA 0.5f
#define C2 15.859712f   // 2*(35.2*0.08)^2

typedef __attribute__((ext_vector_type(4))) float f32x4;
typedef __attribute__((ext_vector_type(8))) short bf16x8;
typedef __attribute__((ext_vector_type(8))) unsigned short u16x8;

static __device__ __forceinline__ unsigned short f2bf(float f) {
    uint32_t u = __float_as_uint(f);
    uint32_t r = (u + 0x7FFFu + ((u >> 16) & 1u)) >> 16;
    return (unsigned short)r;
}
static __device__ __forceinline__ float bf2f(unsigned short h) {
    return __uint_as_float(((uint32_t)h) << 16);
}

// ---------------- prep: split x -> As=[xh|xl], init packed,
//                  split map -> Bs=[mh], m2 ----------------
__global__ __launch_bounds__(256) void k_prep(const float* __restrict__ x,
                                              const float* __restrict__ map,
                                              unsigned short* __restrict__ As,
                                              unsigned short* __restrict__ Bs,
                                              float* __restrict__ m2,
                                              unsigned long long* __restrict__ packed) {
    int bid = blockIdx.x;
    if (bid < BATCH * (D / 8) / 256) {
        // ---- x part: one thread per 8 elements ----
        int g = bid * 256 + threadIdx.x;
        if (g < BATCH) packed[g] = 0xFFFFFFFFFFFFFFFFull;
        int b = g >> 6;
        int k8 = (g & 63) << 3;
        const float* xp = x + (size_t)b * D + k8;
        float4 v0 = *(const float4*)xp;
        float4 v1 = *(const float4*)(xp + 4);
        float vv[8] = {v0.x, v0.y, v0.z, v0.w, v1.x, v1.y, v1.z, v1.w};
        u16x8 hi, lo;
        #pragma unroll
        for (int j = 0; j < 8; j++) {
            unsigned short h = f2bf(vv[j]);
            hi[j] = h;
            lo[j] = f2bf(vv[j] - bf2f(h));
        }
        unsigned short* row = As + (size_t)b * KTOT;
        *(u16x8*)(row + k8) = hi;
        *(u16x8*)(row + 512 + k8) = lo;
    } else {
        // ---- map part: one wave per map row, 4 rows per block ----
        int mb = bid - BATCH * (D / 8) / 256;
        int n = mb * 4 + (threadIdx.x >> 6);
        int lane = threadIdx.x & 63;
        const float* mp = map + (size_t)n * D + lane * 8;
        float4 v0 = *(const float4*)mp;
        float4 v1 = *(const float4*)(mp + 4);
        float vv[8] = {v0.x, v0.y, v0.z, v0.w, v1.x, v1.y, v1.z, v1.w};
        u16x8 hi;
        float s = 0.f;
        #pragma unroll
        for (int j = 0; j < 8; j++) {
            s += vv[j] * vv[j];
            hi[j] = f2bf(vv[j]);
        }
        *(u16x8*)(Bs + (size_t)n * 512 + lane * 8) = hi;
        #pragma unroll
        for (int off = 32; off > 0; off >>= 1) s += __shfl_down(s, off);
        if (lane == 0) m2[n] = s;
    }
}

// ---------------- BMU: bf16 MFMA GEMM + fused argmin ----------------
// dist[b,n] = m2[n] - 2*(xh.mh + xl.mh); argmin_n per row b.
// 128x64 tile, BK=64, 4 waves (2x2, wave tile 64x32), 16x16x32 MFMA.
// Grid 1024 blocks = 4/CU scheduled (~16 waves/CU resident).
// b-stripe XCD ownership: XCD x owns b-tiles [8x,8x+8) for ALL n-tiles ->
// per-XCD working set = 2MB As-stripe + 2MB Bs, L2-resident; packed[]
// atomics XCD-local. Per-dot arithmetic identical to previous round.
#define BM 128
#define BN 64
#define BK 64

__global__ __launch_bounds__(256) void k_bmu(const unsigned short* __restrict__ As,
                                             const unsigned short* __restrict__ Bs,
                                             const float* __restrict__ m2,
                                             unsigned long long* __restrict__ packed) {
    __shared__ unsigned short Al[BM * BK];  // 16 KB
    __shared__ unsigned short Bl[BN * BK];  // 8 KB
    const int xcd = blockIdx.x & 7;
    const int j = blockIdx.x >> 3;           // 0..127
    const int b0 = (xcd * 8 + (j & 7)) * BM; // b-tile within XCD's stripe
    const int n0 = (j >> 3) * BN;            // n-tile 0..15
    const int t = threadIdx.x;
    const int w = t >> 6, l = t & 63;
    const int wm = w >> 1, wn = w & 1;

    f32x4 acc[4][2];
    #pragma unroll
    for (int i = 0; i < 4; i++)
        #pragma unroll
        for (int jj = 0; jj < 2; jj++) acc[i][jj] = (f32x4)(0.f);

    // staging: lane l covers row (l>>3), 16B slot (l&7) of each 8-row chunk.
    // LDS linear; source carries the inverse st-swizzle (slot ^ row&7).
    const int srow = l >> 3;
    const int sslot = (l & 7) ^ (l >> 3);
    // A: wave w stages rows [w*32, w*32+32) -> 4 issues of 8 rows.
    const unsigned short* agp0 = As + (size_t)(b0 + w * 32 + srow) * KTOT + sslot * 8;
    // B: wave w stages rows [w*16, w*16+16) -> 2 issues of 8 rows (stride 512).
    const unsigned short* bgp0 = Bs + (size_t)(n0 + w * 16 + srow) * 512 + sslot * 8;

    for (int kt = 0; kt < KTOT; kt += BK) {
        int ktb = kt & 511;  // Bs dedup: [mh] reused for both K halves
        #pragma unroll
        for (int i = 0; i < 4; i++) {
            __builtin_amdgcn_global_load_lds(
                (const __attribute__((address_space(1))) void*)(agp0 + (size_t)i * 8 * KTOT + kt),
                (__attribute__((address_space(3))) void*)(Al + w * 2048 + i * 512), 16, 0, 0);
        }
        #pragma unroll
        for (int i = 0; i < 2; i++) {
            __builtin_amdgcn_global_load_lds(
                (const __attribute__((address_space(1))) void*)(bgp0 + (size_t)i * 8 * 512 + ktb),
                (__attribute__((address_space(3))) void*)(Bl + w * 1024 + i * 512), 16, 0, 0);
        }
        __syncthreads();

        #pragma unroll
        for (int kk = 0; kk < 2; kk++) {
            bf16x8 af[4], bfr[2];
            #pragma unroll
            for (int mi = 0; mi < 4; mi++) {
                int r = wm * 64 + mi * 16 + (l & 15);
                int slot = kk * 4 + (l >> 4);
                af[mi] = *(const bf16x8*)&Al[r * 64 + ((slot ^ (r & 7)) << 3)];
            }
            #pragma unroll
            for (int nj = 0; nj < 2; nj++) {
                int r = wn * 32 + nj * 16 + (l & 15);
                int slot = kk * 4 + (l >> 4);
                bfr[nj] = *(const bf16x8*)&Bl[r * 64 + ((slot ^ (r & 7)) << 3)];
            }
            #pragma unroll
            for (int mi = 0; mi < 4; mi++)
                #pragma unroll
                for (int nj = 0; nj < 2; nj++)
                    acc[mi][nj] = __builtin_amdgcn_mfma_f32_16x16x32_bf16(
                        af[mi], bfr[nj], acc[mi][nj], 0, 0, 0);
        }
        __syncthreads();
    }

    // ---- fused argmin epilogue ----
    float m2v[2];
    #pragma unroll
    for (int nj = 0; nj < 2; nj++)
        m2v[nj] = m2[n0 + wn * 32 + nj * 16 + (l & 15)];

    #pragma unroll
    for (int mi = 0; mi < 4; mi++) {
        #pragma unroll
        for (int reg = 0; reg < 4; reg++) {
            float best = m2v[0] - 2.0f * acc[mi][0][reg];
            int bi = n0 + wn * 32 + (l & 15);
            {
                float v = m2v[1] - 2.0f * acc[mi][1][reg];
                int n = n0 + wn * 32 + 16 + (l & 15);
                if (v < best) { best = v; bi = n; }
            }
            #pragma unroll
            for (int msk = 1; msk <= 8; msk <<= 1) {
                float ov = __shfl_xor(best, msk);
                int oi = __shfl_xor(bi, msk);
                if (ov < best || (ov == best && oi < bi)) { best = ov; bi = oi; }
            }
            if ((l & 15) == 0) {
                unsigned int fb = __float_as_uint(best);
                fb = (fb & 0x80000000u) ? ~fb : (fb | 0x80000000u);
                unsigned long long key =
                    ((unsigned long long)fb << 32) | (unsigned int)bi;
                int row = b0 + wm * 64 + mi * 16 + (l >> 4) * 4 + reg;
                atomicMin(&packed[row], key);
            }
        }
    }
}

// ---------------- deterministic scatter-sum (reads packed directly) --------
__global__ __launch_bounds__(256) void k_scatter(const float* __restrict__ x,
                                                 const unsigned long long* __restrict__ packed,
                                                 float* __restrict__ S,
                                                 int* __restrict__ cnt) {
    __shared__ int list[BATCH];
    __shared__ int cnts[256];
    __shared__ int offs[256];
    int g = blockIdx.x;
    int t = threadIdx.x;
    int b0 = t * (BATCH / 256);

    int mybmu[BATCH / 256];
    int c = 0;
    #pragma unroll
    for (int i = 0; i < BATCH / 256; i++) {
        mybmu[i] = (int)(packed[b0 + i] & 0xFFFFFFFFull);
        c += (mybmu[i] == g) ? 1 : 0;
    }
    cnts[t] = c;
    offs[t] = c;
    __syncthreads();
    // Hillis-Steele inclusive scan over 256 entries
    #pragma unroll
    for (int s = 1; s < 256; s <<= 1) {
        int v = (t >= s) ? offs[t - s] : 0;
        __syncthreads();
        offs[t] += v;
        __syncthreads();
    }
    int off = offs[t] - cnts[t];  // exclusive
    #pragma unroll
    for (int i = 0; i < BATCH / 256; i++) {
        if (mybmu[i] == g) list[off++] = b0 + i;
    }
    __syncthreads();
    int len = offs[255];

    float acc0 = 0.f, acc1 = 0.f;
    for (int i = 0; i < len; i++) {
        const float* xr = x + (size_t)list[i] * D;
        acc0 += xr[t];
        acc1 += xr[t + 256];
    }
    S[(size_t)g * D + t] = acc0;
    S[(size_t)g * D + t + 256] = acc1;
    if (t == 0) cnt[g] = len;
}

// ---------------- separable conv axis j (+ sum_lr in block (0,0)) ----------
__global__ __launch_bounds__(256) void k_conv1(const float* __restrict__ S,
                                               float* __restrict__ V,
                                               const int* __restrict__ cnt,
                                               float* __restrict__ sum_lr) {
    __shared__ float tbl[GRID_W];
    __shared__ float vc[GRID_W][GRID_W];
    int gi = blockIdx.x;
    int d = blockIdx.y * 256 + threadIdx.x;
    if (threadIdx.x < GRID_W)
        tbl[threadIdx.x] = __expf(-(float)(threadIdx.x * threadIdx.x) / C2);
    __syncthreads();
    float acc[GRID_W];
    #pragma unroll
    for (int nj = 0; nj < GRID_W; nj++) acc[nj] = 0.f;
    for (int gj = 0; gj < GRID_W; gj++) {
        float s = S[(size_t)(gi * GRID_W + gj) * D + d];
        #pragma unroll
        for (int nj = 0; nj < GRID_W; nj++) {
            int dd = nj - gj; dd = dd < 0 ? -dd : dd;
            acc[nj] += tbl[dd] * s;
        }
    }
    #pragma unroll
    for (int nj = 0; nj < GRID_W; nj++)
        V[(size_t)(gi * GRID_W + nj) * D + d] = acc[nj];

    // ---- sum_lr (separable over counts), one block does it all ----
    if (blockIdx.x == 0 && blockIdx.y == 0) {
        int t = threadIdx.x;
        #pragma unroll
        for (int j = 0; j < 4; j++) {
            int idx = t * 4 + j;
            int a = idx >> 5, b = idx & 31;
            float s = 0.f;
            for (int gj = 0; gj < GRID_W; gj++) {
                int dd = gj - b; dd = dd < 0 ? -dd : dd;
                s += tbl[dd] * (float)cnt[a * GRID_W + gj];
            }
            vc[a][b] = s;
        }
        __syncthreads();
        #pragma unroll
        for (int j = 0; j < 4; j++) {
            int idx = t * 4 + j;
            int a = idx >> 5, b = idx & 31;
            float s2 = 0.f;
            for (int gg = 0; gg < GRID_W; gg++) {
                int dd = gg - a; dd = dd < 0 ? -dd : dd;
                s2 += tbl[dd] * vc[gg][b];
            }
            sum_lr[idx] = ALPHA * s2;
        }
    }
}

// ---------------- separable conv axis i + epilogue ----------------
__global__ __launch_bounds__(256) void k_conv2(const float* __restrict__ V,
                                               const float* __restrict__ map,
                                               const float* __restrict__ sum_lr,
                                               float* __restrict__ out) {
    __shared__ float tbl[GRID_W];
    int nj = blockIdx.x;
    int d = blockIdx.y * 256 + threadIdx.x;
    if (threadIdx.x < GRID_W)
        tbl[threadIdx.x] = __expf(-(float)(threadIdx.x * threadIdx.x) / C2);
    __syncthreads();
    float acc[GRID_W];
    #pragma unroll
    for (int ni = 0; ni < GRID_W; ni++) acc[ni] = 0.f;
    for (int gi = 0; gi < GRID_W; gi++) {
        float v = V[(size_t)(gi * GRID_W + nj) * D + d];
        #pragma unroll
        for (int ni = 0; ni < GRID_W; ni++) {
            int dd = ni - gi; dd = dd < 0 ? -dd : dd;
            acc[ni] += tbl[dd] * v;
        }
    }
    #pragma unroll
    for (int ni = 0; ni < GRID_W; ni++) {
        int n = ni * GRID_W + nj;
        out[(size_t)n * D + d] =
            map[(size_t)n * D + d] * (1.0f - sum_lr[n]) + ALPHA * acc[ni];
    }
}

// ---------------- launcher ----------------
extern "C" void kernel_launch(void* const* d_in, const int* in_sizes, int n_in,
                              void* d_out, int out_size, void* d_ws, size_t ws_size,
                              hipStream_t stream) {
    (void)in_sizes; (void)n_in; (void)out_size; (void)ws_size;
    const float* x = (const float*)d_in[0];
    const float* map = (const float*)d_in[1];
    float* out = (float*)d_out;

    char* ws = (char*)d_ws;
    unsigned long long* packed = (unsigned long long*)(ws);          // 64 KB
    float* m2 = (float*)(ws + 65536);                                // 4 KB
    int* cnt = (int*)(ws + 69632);                                   // 4 KB
    float* sum_lr = (float*)(ws + 73728);                            // 4 KB
    float* S = (float*)(ws + 77824);                                 // 2 MB
    float* V = (float*)(ws + 2174976);                               // 2 MB
    unsigned short* As = (unsigned short*)(ws + 4272128);            // 16 MB
    unsigned short* Bs = (unsigned short*)(ws + 21049344);           // 1 MB

    k_prep<<<BATCH * (D / 8) / 256 + NMAP / 4, 256, 0, stream>>>(x, map, As, Bs, m2, packed);
    k_bmu<<<(BATCH / BM) * (NMAP / BN), 256, 0, stream>>>(As, Bs, m2, packed);
    k_scatter<<<NMAP, 256, 0, stream>>>(x, packed, S, cnt);
    k_conv1<<<dim3(GRID_W, D / 256), 256, 0, stream>>>(S, V, cnt, sum_lr);
    k_conv2<<<dim3(GRID_W, D / 256), 256, 0, stream>>>(V, map, sum_lr, out);
}

// Round 7
// 97.655 us; speedup vs baseline: 2.6358x; 1.0075x over previous
//
#include <hip/hip_runtime.h>
#include <stdint.h>

#define D 512
#define KTOT 1024       // A = [xh | xl]; B dedup'd to [mh] (stride 512)
#define BATCH 8192
#define NMAP 1024
#define GRID_W 32
#define ALPHA 0.5f
#define C2 15.859712f   // 2*(35.2*0.08)^2
#define DC 8            // d-chunk per fused-conv block

typedef __attribute__((ext_vector_type(4))) float f32x4;
typedef __attribute__((ext_vector_type(8))) short bf16x8;
typedef __attribute__((ext_vector_type(8))) unsigned short u16x8;

static __device__ __forceinline__ unsigned short f2bf(float f) {
    uint32_t u = __float_as_uint(f);
    uint32_t r = (u + 0x7FFFu + ((u >> 16) & 1u)) >> 16;
    return (unsigned short)r;
}
static __device__ __forceinline__ float bf2f(unsigned short h) {
    return __uint_as_float(((uint32_t)h) << 16);
}

// ---------------- prep: split x -> As=[xh|xl], init packed,
//                  split map -> Bs=[mh], m2 ----------------
__global__ __launch_bounds__(256) void k_prep(const float* __restrict__ x,
                                              const float* __restrict__ map,
                                              unsigned short* __restrict__ As,
                                              unsigned short* __restrict__ Bs,
                                              float* __restrict__ m2,
                                              unsigned long long* __restrict__ packed) {
    int bid = blockIdx.x;
    if (bid < BATCH * (D / 8) / 256) {
        // ---- x part: one thread per 8 elements ----
        int g = bid * 256 + threadIdx.x;
        if (g < BATCH) packed[g] = 0xFFFFFFFFFFFFFFFFull;
        int b = g >> 6;
        int k8 = (g & 63) << 3;
        const float* xp = x + (size_t)b * D + k8;
        float4 v0 = *(const float4*)xp;
        float4 v1 = *(const float4*)(xp + 4);
        float vv[8] = {v0.x, v0.y, v0.z, v0.w, v1.x, v1.y, v1.z, v1.w};
        u16x8 hi, lo;
        #pragma unroll
        for (int j = 0; j < 8; j++) {
            unsigned short h = f2bf(vv[j]);
            hi[j] = h;
            lo[j] = f2bf(vv[j] - bf2f(h));
        }
        unsigned short* row = As + (size_t)b * KTOT;
        *(u16x8*)(row + k8) = hi;
        *(u16x8*)(row + 512 + k8) = lo;
    } else {
        // ---- map part: one wave per map row, 4 rows per block ----
        int mb = bid - BATCH * (D / 8) / 256;
        int n = mb * 4 + (threadIdx.x >> 6);
        int lane = threadIdx.x & 63;
        const float* mp = map + (size_t)n * D + lane * 8;
        float4 v0 = *(const float4*)mp;
        float4 v1 = *(const float4*)(mp + 4);
        float vv[8] = {v0.x, v0.y, v0.z, v0.w, v1.x, v1.y, v1.z, v1.w};
        u16x8 hi;
        float s = 0.f;
        #pragma unroll
        for (int j = 0; j < 8; j++) {
            s += vv[j] * vv[j];
            hi[j] = f2bf(vv[j]);
        }
        *(u16x8*)(Bs + (size_t)n * 512 + lane * 8) = hi;
        #pragma unroll
        for (int off = 32; off > 0; off >>= 1) s += __shfl_down(s, off);
        if (lane == 0) m2[n] = s;
    }
}

// ---------------- BMU: bf16 MFMA GEMM + fused argmin ----------------
// dist[b,n] = m2[n] - 2*(xh.mh + xl.mh); argmin_n per row b.
// 128x64 tile, BK=64, 4 waves (2x2, wave tile 64x32), 16x16x32 MFMA.
// b-stripe XCD ownership; st-swizzled LDS via pre-swizzled source.
#define BM 128
#define BN 64
#define BK 64

__global__ __launch_bounds__(256) void k_bmu(const unsigned short* __restrict__ As,
                                             const unsigned short* __restrict__ Bs,
                                             const float* __restrict__ m2,
                                             unsigned long long* __restrict__ packed) {
    __shared__ unsigned short Al[BM * BK];  // 16 KB
    __shared__ unsigned short Bl[BN * BK];  // 8 KB
    const int xcd = blockIdx.x & 7;
    const int j = blockIdx.x >> 3;           // 0..127
    const int b0 = (xcd * 8 + (j & 7)) * BM; // b-tile within XCD's stripe
    const int n0 = (j >> 3) * BN;            // n-tile 0..15
    const int t = threadIdx.x;
    const int w = t >> 6, l = t & 63;
    const int wm = w >> 1, wn = w & 1;

    f32x4 acc[4][2];
    #pragma unroll
    for (int i = 0; i < 4; i++)
        #pragma unroll
        for (int jj = 0; jj < 2; jj++) acc[i][jj] = (f32x4)(0.f);

    const int srow = l >> 3;
    const int sslot = (l & 7) ^ (l >> 3);
    const unsigned short* agp0 = As + (size_t)(b0 + w * 32 + srow) * KTOT + sslot * 8;
    const unsigned short* bgp0 = Bs + (size_t)(n0 + w * 16 + srow) * 512 + sslot * 8;

    for (int kt = 0; kt < KTOT; kt += BK) {
        int ktb = kt & 511;  // Bs dedup: [mh] reused for both K halves
        #pragma unroll
        for (int i = 0; i < 4; i++) {
            __builtin_amdgcn_global_load_lds(
                (const __attribute__((address_space(1))) void*)(agp0 + (size_t)i * 8 * KTOT + kt),
                (__attribute__((address_space(3))) void*)(Al + w * 2048 + i * 512), 16, 0, 0);
        }
        #pragma unroll
        for (int i = 0; i < 2; i++) {
            __builtin_amdgcn_global_load_lds(
                (const __attribute__((address_space(1))) void*)(bgp0 + (size_t)i * 8 * 512 + ktb),
                (__attribute__((address_space(3))) void*)(Bl + w * 1024 + i * 512), 16, 0, 0);
        }
        __syncthreads();

        #pragma unroll
        for (int kk = 0; kk < 2; kk++) {
            bf16x8 af[4], bfr[2];
            #pragma unroll
            for (int mi = 0; mi < 4; mi++) {
                int r = wm * 64 + mi * 16 + (l & 15);
                int slot = kk * 4 + (l >> 4);
                af[mi] = *(const bf16x8*)&Al[r * 64 + ((slot ^ (r & 7)) << 3)];
            }
            #pragma unroll
            for (int nj = 0; nj < 2; nj++) {
                int r = wn * 32 + nj * 16 + (l & 15);
                int slot = kk * 4 + (l >> 4);
                bfr[nj] = *(const bf16x8*)&Bl[r * 64 + ((slot ^ (r & 7)) << 3)];
            }
            #pragma unroll
            for (int mi = 0; mi < 4; mi++)
                #pragma unroll
                for (int nj = 0; nj < 2; nj++)
                    acc[mi][nj] = __builtin_amdgcn_mfma_f32_16x16x32_bf16(
                        af[mi], bfr[nj], acc[mi][nj], 0, 0, 0);
        }
        __syncthreads();
    }

    // ---- fused argmin epilogue ----
    float m2v[2];
    #pragma unroll
    for (int nj = 0; nj < 2; nj++)
        m2v[nj] = m2[n0 + wn * 32 + nj * 16 + (l & 15)];

    #pragma unroll
    for (int mi = 0; mi < 4; mi++) {
        #pragma unroll
        for (int reg = 0; reg < 4; reg++) {
            float best = m2v[0] - 2.0f * acc[mi][0][reg];
            int bi = n0 + wn * 32 + (l & 15);
            {
                float v = m2v[1] - 2.0f * acc[mi][1][reg];
                int n = n0 + wn * 32 + 16 + (l & 15);
                if (v < best) { best = v; bi = n; }
            }
            #pragma unroll
            for (int msk = 1; msk <= 8; msk <<= 1) {
                float ov = __shfl_xor(best, msk);
                int oi = __shfl_xor(bi, msk);
                if (ov < best || (ov == best && oi < bi)) { best = ov; bi = oi; }
            }
            if ((l & 15) == 0) {
                unsigned int fb = __float_as_uint(best);
                fb = (fb & 0x80000000u) ? ~fb : (fb | 0x80000000u);
                unsigned long long key =
                    ((unsigned long long)fb << 32) | (unsigned int)bi;
                int row = b0 + wm * 64 + mi * 16 + (l >> 4) * 4 + reg;
                atomicMin(&packed[row], key);
            }
        }
    }
}

// ---------------- deterministic scatter-sum (2-way ILP) ----------------
__global__ __launch_bounds__(256) void k_scatter(const float* __restrict__ x,
                                                 const unsigned long long* __restrict__ packed,
                                                 float* __restrict__ S,
                                                 int* __restrict__ cnt) {
    __shared__ int list[BATCH];
    __shared__ int cnts[256];
    __shared__ int offs[256];
    int g = blockIdx.x;
    int t = threadIdx.x;
    int b0 = t * (BATCH / 256);

    int mybmu[BATCH / 256];
    int c = 0;
    #pragma unroll
    for (int i = 0; i < BATCH / 256; i++) {
        mybmu[i] = (int)(packed[b0 + i] & 0xFFFFFFFFull);
        c += (mybmu[i] == g) ? 1 : 0;
    }
    cnts[t] = c;
    offs[t] = c;
    __syncthreads();
    #pragma unroll
    for (int s = 1; s < 256; s <<= 1) {
        int v = (t >= s) ? offs[t - s] : 0;
        __syncthreads();
        offs[t] += v;
        __syncthreads();
    }
    int off = offs[t] - cnts[t];
    #pragma unroll
    for (int i = 0; i < BATCH / 256; i++) {
        if (mybmu[i] == g) list[off++] = b0 + i;
    }
    __syncthreads();
    int len = offs[255];

    float a0 = 0.f, a1 = 0.f, c0 = 0.f, c1 = 0.f;
    int i = 0;
    for (; i + 2 <= len; i += 2) {
        const float* xr0 = x + (size_t)list[i] * D;
        const float* xr1 = x + (size_t)list[i + 1] * D;
        a0 += xr0[t]; a1 += xr0[t + 256];
        c0 += xr1[t]; c1 += xr1[t + 256];
    }
    if (i < len) {
        const float* xr = x + (size_t)list[i] * D;
        a0 += xr[t]; a1 += xr[t + 256];
    }
    S[(size_t)g * D + t] = a0 + c0;
    S[(size_t)g * D + t + 256] = a1 + c1;
    if (t == 0) cnt[g] = len;
}

// ---------------- fused conv: j-conv + i-conv + sum_lr + epilogue ----------
// Block owns d-chunk [d0, d0+8). Thread owns (nj = (t>>3)&31, dc = t&7).
// Fixing (nj,dc), both convolutions' dependency chain is thread-local:
// vreg[gi] = sum_gj tbl|nj-gj| * S[gi*32+gj][dc]   (j-conv, from LDS)
// out[ni*32+nj][dc] = map*(1-slr) + A*sum_gi tbl|ni-gi| * vreg[gi]
// Same summation order as the old conv1/conv2/sumlr -> identical arithmetic.
__global__ __launch_bounds__(256) void k_conv(const float* __restrict__ S,
                                              const int* __restrict__ cnt,
                                              const float* __restrict__ map,
                                              float* __restrict__ out) {
    __shared__ float T[NMAP][DC + 1];      // 36.9 KB, pad avoids bank alias
    __shared__ float tbl[GRID_W];
    __shared__ float vcB[GRID_W][GRID_W];  // vcB[gi][nj] for sum_lr
    int t = threadIdx.x;
    int d0 = blockIdx.x * DC;
    if (t < GRID_W) tbl[t] = __expf(-(float)(t * t) / C2);
    // load S[:, d0:d0+8): 1024 rows x 2 float4
    #pragma unroll
    for (int p = 0; p < 8; p++) {
        int idx = p * 256 + t;
        int row = idx >> 1, half = (idx & 1) * 4;
        float4 v = *(const float4*)(S + (size_t)row * D + d0 + half);
        T[row][half + 0] = v.x; T[row][half + 1] = v.y;
        T[row][half + 2] = v.z; T[row][half + 3] = v.w;
    }
    __syncthreads();
    // vcB[a][b] = sum_gj tbl|gj-b| * cnt[a*32+gj]  (4 cells per thread)
    #pragma unroll
    for (int jj = 0; jj < 4; jj++) {
        int idx = t * 4 + jj;
        int a = idx >> 5, b = idx & 31;
        float s = 0.f;
        for (int gj = 0; gj < GRID_W; gj++) {
            int dd = gj - b; dd = dd < 0 ? -dd : dd;
            s += tbl[dd] * (float)cnt[a * GRID_W + gj];
        }
        vcB[a][b] = s;
    }
    __syncthreads();

    int nj = (t >> 3) & 31;
    int dc = t & 7;
    // j-conv into registers (LDS reads broadcast across the 8 nj-groups)
    float vreg[GRID_W];
    #pragma unroll
    for (int gi = 0; gi < GRID_W; gi++) {
        float s = 0.f;
        #pragma unroll
        for (int gj = 0; gj < GRID_W; gj++) {
            int dd = nj - gj; dd = dd < 0 ? -dd : dd;
            s += tbl[dd] * T[gi * GRID_W + gj][dc];
        }
        vreg[gi] = s;
    }
    // i-conv + sum_lr + epilogue, all register/LDS-broadcast
    #pragma unroll
    for (int ni = 0; ni < GRID_W; ni++) {
        float u = 0.f;
        float s2 = 0.f;
        #pragma unroll
        for (int gi = 0; gi < GRID_W; gi++) {
            int dd = ni - gi; dd = dd < 0 ? -dd : dd;
            u += tbl[dd] * vreg[gi];
            s2 += tbl[dd] * vcB[gi][nj];
        }
        float slr = ALPHA * s2;
        int n = ni * GRID_W + nj;
        out[(size_t)n * D + d0 + dc] =
            map[(size_t)n * D + d0 + dc] * (1.0f - slr) + ALPHA * u;
    }
}

// ---------------- launcher ----------------
extern "C" void kernel_launch(void* const* d_in, const int* in_sizes, int n_in,
                              void* d_out, int out_size, void* d_ws, size_t ws_size,
                              hipStream_t stream) {
    (void)in_sizes; (void)n_in; (void)out_size; (void)ws_size;
    const float* x = (const float*)d_in[0];
    const float* map = (const float*)d_in[1];
    float* out = (float*)d_out;

    char* ws = (char*)d_ws;
    unsigned long long* packed = (unsigned long long*)(ws);          // 64 KB
    float* m2 = (float*)(ws + 65536);                                // 4 KB
    int* cnt = (int*)(ws + 69632);                                   // 4 KB
    float* S = (float*)(ws + 73728);                                 // 2 MB
    unsigned short* As = (unsigned short*)(ws + 2170880);            // 16 MB
    unsigned short* Bs = (unsigned short*)(ws + 18948096);           // 1 MB

    k_prep<<<BATCH * (D / 8) / 256 + NMAP / 4, 256, 0, stream>>>(x, map, As, Bs, m2, packed);
    k_bmu<<<(BATCH / BM) * (NMAP / BN), 256, 0, stream>>>(As, Bs, m2, packed);
    k_scatter<<<NMAP, 256, 0, stream>>>(x, packed, S, cnt);
    k_conv<<<D / DC, 256, 0, stream>>>(S, cnt, map, out);
}

// Round 8
// 83.503 us; speedup vs baseline: 3.0825x; 1.1695x over previous
//
#include <hip/hip_runtime.h>
#include <stdint.h>

#define D 512
#define KTOT 512        // plain fp16 GEMM: A=fp16(x), B=fp16(map)
#define BATCH 8192
#define NMAP 1024
#define GRID_W 32
#define ALPHA 0.5f
#define C2 15.859712f   // 2*(35.2*0.08)^2

typedef __attribute__((ext_vector_type(4))) float f32x4;
typedef __attribute__((ext_vector_type(8))) _Float16 f16x8;
typedef __attribute__((ext_vector_type(8))) unsigned short u16x8;

static __device__ __forceinline__ unsigned short f2h(float f) {
    union { _Float16 h; unsigned short u; } cv;
    cv.h = (_Float16)f;   // v_cvt_f16_f32, RTN, deterministic
    return cv.u;
}

// ---------------- prep: As=fp16(x), Bs=fp16(map), m2, packed-init ----------
__global__ __launch_bounds__(256) void k_prep(const float* __restrict__ x,
                                              const float* __restrict__ map,
                                              unsigned short* __restrict__ As,
                                              unsigned short* __restrict__ Bs,
                                              float* __restrict__ m2,
                                              unsigned long long* __restrict__ packed) {
    int bid = blockIdx.x;
    if (bid < BATCH * (D / 8) / 256) {
        // ---- x part: one thread per 8 elements ----
        int g = bid * 256 + threadIdx.x;
        if (g < BATCH) packed[g] = 0xFFFFFFFFFFFFFFFFull;
        int b = g >> 6;
        int k8 = (g & 63) << 3;
        const float* xp = x + (size_t)b * D + k8;
        float4 v0 = *(const float4*)xp;
        float4 v1 = *(const float4*)(xp + 4);
        float vv[8] = {v0.x, v0.y, v0.z, v0.w, v1.x, v1.y, v1.z, v1.w};
        u16x8 hi;
        #pragma unroll
        for (int j = 0; j < 8; j++) hi[j] = f2h(vv[j]);
        *(u16x8*)(As + (size_t)b * KTOT + k8) = hi;
    } else {
        // ---- map part: one wave per map row, 4 rows per block ----
        int mb = bid - BATCH * (D / 8) / 256;
        int n = mb * 4 + (threadIdx.x >> 6);
        int lane = threadIdx.x & 63;
        const float* mp = map + (size_t)n * D + lane * 8;
        float4 v0 = *(const float4*)mp;
        float4 v1 = *(const float4*)(mp + 4);
        float vv[8] = {v0.x, v0.y, v0.z, v0.w, v1.x, v1.y, v1.z, v1.w};
        u16x8 hi;
        float s = 0.f;
        #pragma unroll
        for (int j = 0; j < 8; j++) {
            s += vv[j] * vv[j];
            hi[j] = f2h(vv[j]);
        }
        *(u16x8*)(Bs + (size_t)n * KTOT + lane * 8) = hi;
        #pragma unroll
        for (int off = 32; off > 0; off >>= 1) s += __shfl_down(s, off);
        if (lane == 0) m2[n] = s;
    }
}

// ---------------- BMU: fp16 MFMA GEMM + fused argmin ----------------
// dist[b,n] = m2[n] - 2*dot(fp16(x[b]), fp16(map[n])); argmin_n per row b.
// 128x64 tile, BK=64, 4 waves (2x2, wave tile 64x32), 16x16x32 f16 MFMA.
// b-stripe XCD ownership; st-swizzled LDS via pre-swizzled source.
#define BM 128
#define BN 64
#define BK 64

__global__ __launch_bounds__(256) void k_bmu(const unsigned short* __restrict__ As,
                                             const unsigned short* __restrict__ Bs,
                                             const float* __restrict__ m2,
                                             unsigned long long* __restrict__ packed) {
    __shared__ unsigned short Al[BM * BK];  // 16 KB
    __shared__ unsigned short Bl[BN * BK];  // 8 KB
    const int xcd = blockIdx.x & 7;
    const int j = blockIdx.x >> 3;           // 0..127
    const int b0 = (xcd * 8 + (j & 7)) * BM; // b-tile within XCD's stripe
    const int n0 = (j >> 3) * BN;            // n-tile 0..15
    const int t = threadIdx.x;
    const int w = t >> 6, l = t & 63;
    const int wm = w >> 1, wn = w & 1;

    f32x4 acc[4][2];
    #pragma unroll
    for (int i = 0; i < 4; i++)
        #pragma unroll
        for (int jj = 0; jj < 2; jj++) acc[i][jj] = (f32x4)(0.f);

    const int srow = l >> 3;
    const int sslot = (l & 7) ^ (l >> 3);
    const unsigned short* agp0 = As + (size_t)(b0 + w * 32 + srow) * KTOT + sslot * 8;
    const unsigned short* bgp0 = Bs + (size_t)(n0 + w * 16 + srow) * KTOT + sslot * 8;

    for (int kt = 0; kt < KTOT; kt += BK) {
        #pragma unroll
        for (int i = 0; i < 4; i++) {
            __builtin_amdgcn_global_load_lds(
                (const __attribute__((address_space(1))) void*)(agp0 + (size_t)i * 8 * KTOT + kt),
                (__attribute__((address_space(3))) void*)(Al + w * 2048 + i * 512), 16, 0, 0);
        }
        #pragma unroll
        for (int i = 0; i < 2; i++) {
            __builtin_amdgcn_global_load_lds(
                (const __attribute__((address_space(1))) void*)(bgp0 + (size_t)i * 8 * KTOT + kt),
                (__attribute__((address_space(3))) void*)(Bl + w * 1024 + i * 512), 16, 0, 0);
        }
        __syncthreads();

        #pragma unroll
        for (int kk = 0; kk < 2; kk++) {
            f16x8 af[4], bfr[2];
            #pragma unroll
            for (int mi = 0; mi < 4; mi++) {
                int r = wm * 64 + mi * 16 + (l & 15);
                int slot = kk * 4 + (l >> 4);
                af[mi] = *(const f16x8*)&Al[r * 64 + ((slot ^ (r & 7)) << 3)];
            }
            #pragma unroll
            for (int nj = 0; nj < 2; nj++) {
                int r = wn * 32 + nj * 16 + (l & 15);
                int slot = kk * 4 + (l >> 4);
                bfr[nj] = *(const f16x8*)&Bl[r * 64 + ((slot ^ (r & 7)) << 3)];
            }
            #pragma unroll
            for (int mi = 0; mi < 4; mi++)
                #pragma unroll
                for (int nj = 0; nj < 2; nj++)
                    acc[mi][nj] = __builtin_amdgcn_mfma_f32_16x16x32_f16(
                        af[mi], bfr[nj], acc[mi][nj], 0, 0, 0);
        }
        __syncthreads();
    }

    // ---- fused argmin epilogue ----
    float m2v[2];
    #pragma unroll
    for (int nj = 0; nj < 2; nj++)
        m2v[nj] = m2[n0 + wn * 32 + nj * 16 + (l & 15)];

    #pragma unroll
    for (int mi = 0; mi < 4; mi++) {
        #pragma unroll
        for (int reg = 0; reg < 4; reg++) {
            float best = m2v[0] - 2.0f * acc[mi][0][reg];
            int bi = n0 + wn * 32 + (l & 15);
            {
                float v = m2v[1] - 2.0f * acc[mi][1][reg];
                int n = n0 + wn * 32 + 16 + (l & 15);
                if (v < best) { best = v; bi = n; }
            }
            #pragma unroll
            for (int msk = 1; msk <= 8; msk <<= 1) {
                float ov = __shfl_xor(best, msk);
                int oi = __shfl_xor(bi, msk);
                if (ov < best || (ov == best && oi < bi)) { best = ov; bi = oi; }
            }
            if ((l & 15) == 0) {
                unsigned int fb = __float_as_uint(best);
                fb = (fb & 0x80000000u) ? ~fb : (fb | 0x80000000u);
                unsigned long long key =
                    ((unsigned long long)fb << 32) | (unsigned int)bi;
                int row = b0 + wm * 64 + mi * 16 + (l >> 4) * 4 + reg;
                atomicMin(&packed[row], key);
            }
        }
    }
}

// ---------------- deterministic scatter-sum (2-way ILP) ----------------
__global__ __launch_bounds__(256) void k_scatter(const float* __restrict__ x,
                                                 const unsigned long long* __restrict__ packed,
                                                 float* __restrict__ S,
                                                 int* __restrict__ cnt) {
    __shared__ int list[BATCH];
    __shared__ int cnts[256];
    __shared__ int offs[256];
    int g = blockIdx.x;
    int t = threadIdx.x;
    int b0 = t * (BATCH / 256);

    int mybmu[BATCH / 256];
    int c = 0;
    #pragma unroll
    for (int i = 0; i < BATCH / 256; i++) {
        mybmu[i] = (int)(packed[b0 + i] & 0xFFFFFFFFull);
        c += (mybmu[i] == g) ? 1 : 0;
    }
    cnts[t] = c;
    offs[t] = c;
    __syncthreads();
    #pragma unroll
    for (int s = 1; s < 256; s <<= 1) {
        int v = (t >= s) ? offs[t - s] : 0;
        __syncthreads();
        offs[t] += v;
        __syncthreads();
    }
    int off = offs[t] - cnts[t];
    #pragma unroll
    for (int i = 0; i < BATCH / 256; i++) {
        if (mybmu[i] == g) list[off++] = b0 + i;
    }
    __syncthreads();
    int len = offs[255];

    float a0 = 0.f, a1 = 0.f, c0 = 0.f, c1 = 0.f;
    int i = 0;
    for (; i + 2 <= len; i += 2) {
        const float* xr0 = x + (size_t)list[i] * D;
        const float* xr1 = x + (size_t)list[i + 1] * D;
        a0 += xr0[t]; a1 += xr0[t + 256];
        c0 += xr1[t]; c1 += xr1[t + 256];
    }
    if (i < len) {
        const float* xr = x + (size_t)list[i] * D;
        a0 += xr[t]; a1 += xr[t + 256];
    }
    S[(size_t)g * D + t] = a0 + c0;
    S[(size_t)g * D + t + 256] = a1 + c1;
    if (t == 0) cnt[g] = len;
}

// ---------------- separable conv axis j (+ sum_lr in block (0,0)) ----------
__global__ __launch_bounds__(256) void k_conv1(const float* __restrict__ S,
                                               float* __restrict__ V,
                                               const int* __restrict__ cnt,
                                               float* __restrict__ sum_lr) {
    __shared__ float tbl[GRID_W];
    __shared__ float vc[GRID_W][GRID_W];
    int gi = blockIdx.x;
    int d = blockIdx.y * 256 + threadIdx.x;
    if (threadIdx.x < GRID_W)
        tbl[threadIdx.x] = __expf(-(float)(threadIdx.x * threadIdx.x) / C2);
    __syncthreads();
    float acc[GRID_W];
    #pragma unroll
    for (int nj = 0; nj < GRID_W; nj++) acc[nj] = 0.f;
    for (int gj = 0; gj < GRID_W; gj++) {
        float s = S[(size_t)(gi * GRID_W + gj) * D + d];
        #pragma unroll
        for (int nj = 0; nj < GRID_W; nj++) {
            int dd = nj - gj; dd = dd < 0 ? -dd : dd;
            acc[nj] += tbl[dd] * s;
        }
    }
    #pragma unroll
    for (int nj = 0; nj < GRID_W; nj++)
        V[(size_t)(gi * GRID_W + nj) * D + d] = acc[nj];

    // ---- sum_lr (separable over counts), one block does it all ----
    if (blockIdx.x == 0 && blockIdx.y == 0) {
        int t = threadIdx.x;
        #pragma unroll
        for (int j = 0; j < 4; j++) {
            int idx = t * 4 + j;
            int a = idx >> 5, b = idx & 31;
            float s = 0.f;
            for (int gj = 0; gj < GRID_W; gj++) {
                int dd = gj - b; dd = dd < 0 ? -dd : dd;
                s += tbl[dd] * (float)cnt[a * GRID_W + gj];
            }
            vc[a][b] = s;
        }
        __syncthreads();
        #pragma unroll
        for (int j = 0; j < 4; j++) {
            int idx = t * 4 + j;
            int a = idx >> 5, b = idx & 31;
            float s2 = 0.f;
            for (int gg = 0; gg < GRID_W; gg++) {
                int dd = gg - a; dd = dd < 0 ? -dd : dd;
                s2 += tbl[dd] * vc[gg][b];
            }
            sum_lr[idx] = ALPHA * s2;
        }
    }
}

// ---------------- separable conv axis i + epilogue ----------------
__global__ __launch_bounds__(256) void k_conv2(const float* __restrict__ V,
                                               const float* __restrict__ map,
                                               const float* __restrict__ sum_lr,
                                               float* __restrict__ out) {
    __shared__ float tbl[GRID_W];
    int nj = blockIdx.x;
    int d = blockIdx.y * 256 + threadIdx.x;
    if (threadIdx.x < GRID_W)
        tbl[threadIdx.x] = __expf(-(float)(threadIdx.x * threadIdx.x) / C2);
    __syncthreads();
    float acc[GRID_W];
    #pragma unroll
    for (int ni = 0; ni < GRID_W; ni++) acc[ni] = 0.f;
    for (int gi = 0; gi < GRID_W; gi++) {
        float v = V[(size_t)(gi * GRID_W + nj) * D + d];
        #pragma unroll
        for (int ni = 0; ni < GRID_W; ni++) {
            int dd = ni - gi; dd = dd < 0 ? -dd : dd;
            acc[ni] += tbl[dd] * v;
        }
    }
    #pragma unroll
    for (int ni = 0; ni < GRID_W; ni++) {
        int n = ni * GRID_W + nj;
        out[(size_t)n * D + d] =
            map[(size_t)n * D + d] * (1.0f - sum_lr[n]) + ALPHA * acc[ni];
    }
}

// ---------------- launcher ----------------
extern "C" void kernel_launch(void* const* d_in, const int* in_sizes, int n_in,
                              void* d_out, int out_size, void* d_ws, size_t ws_size,
                              hipStream_t stream) {
    (void)in_sizes; (void)n_in; (void)out_size; (void)ws_size;
    const float* x = (const float*)d_in[0];
    const float* map = (const float*)d_in[1];
    float* out = (float*)d_out;

    char* ws = (char*)d_ws;
    unsigned long long* packed = (unsigned long long*)(ws);          // 64 KB
    float* m2 = (float*)(ws + 65536);                                // 4 KB
    int* cnt = (int*)(ws + 69632);                                   // 4 KB
    float* sum_lr = (float*)(ws + 73728);                            // 4 KB
    float* S = (float*)(ws + 77824);                                 // 2 MB
    float* V = (float*)(ws + 2174976);                               // 2 MB
    unsigned short* As = (unsigned short*)(ws + 4272128);            // 8 MB
    unsigned short* Bs = (unsigned short*)(ws + 12660736);           // 1 MB

    k_prep<<<BATCH * (D / 8) / 256 + NMAP / 4, 256, 0, stream>>>(x, map, As, Bs, m2, packed);
    k_bmu<<<(BATCH / BM) * (NMAP / BN), 256, 0, stream>>>(As, Bs, m2, packed);
    k_scatter<<<NMAP, 256, 0, stream>>>(x, packed, S, cnt);
    k_conv1<<<dim3(GRID_W, D / 256), 256, 0, stream>>>(S, V, cnt, sum_lr);
    k_conv2<<<dim3(GRID_W, D / 256), 256, 0, stream>>>(V, map, sum_lr, out);
}